// Round 8
// baseline (220.519 us; speedup 1.0000x reference)
//
#include <hip/hip_runtime.h>
#include <hip/hip_bf16.h>

// AtomPoolingLayer: M=512, N=128 atoms, F=512, HID=128. fp32 in, fp32 out.
// out[m,f] = sum_n sigmoid(relu(h[m,n,:]@W1+b1)@W2+b2) * h[m,n,f]
//
// R7 lesson: barrier-locked LDS K-loop phases SUM pipe costs; B-LDS round
// trip + imperfect swizzles added LDS serialization. R8: minimal-sync
// design - 2 barriers total, B-frags straight from L2-resident W1Tt
// (no B LDS), A staged once (coalesced), independent waves, atomic merge.

typedef unsigned short u16;
typedef unsigned int u32;
typedef __bf16 bf16x8 __attribute__((ext_vector_type(8)));
typedef float f32x4 __attribute__((ext_vector_type(4)));
typedef u32 u32x4 __attribute__((ext_vector_type(4)));

#define M_MOL 512
#define F_DIM 512
#define HID_DIM 128
#define ABLK 32            // atoms per block
#define NBLK (M_MOL * 4)   // 2048 blocks, 4 per molecule

static __device__ __forceinline__ u16 f2bf(float x) {
  u32 u = __float_as_uint(x);
  u32 r = (u + 0x7fffu + ((u >> 16) & 1u)) >> 16;  // RNE
  return (u16)r;
}
// repack two fp32x4 -> bf16x8 by truncation (|rel err| <= 2^-8)
static __device__ __forceinline__ bf16x8 pack8(u32x4 a, u32x4 b) {
  u32x4 r;
  r[0] = (a[0] >> 16) | (a[1] & 0xffff0000u);
  r[1] = (a[2] >> 16) | (a[3] & 0xffff0000u);
  r[2] = (b[0] >> 16) | (b[1] & 0xffff0000u);
  r[3] = (b[2] >> 16) | (b[3] & 0xffff0000u);
  return __builtin_bit_cast(bf16x8, r);
}

// ---- Kernel 1: W1 fp32 [F=512][HID=128] -> W1Tt bf16 [16][4][128][8] ----
__global__ __launch_bounds__(256) void transpose_w1(const float* __restrict__ W1,
                                                    u16* __restrict__ W1Tt) {
  __shared__ float tile[64][65];
  const int k0 = blockIdx.x * 64;
  const int n0 = blockIdx.y * 64;
  const int t = threadIdx.x;
  #pragma unroll
  for (int i = 0; i < 16; ++i) {
    const int lin = i * 256 + t;
    const int lr = lin >> 6, lc = lin & 63;
    tile[lc][lr] = W1[(size_t)(k0 + lr) * HID_DIM + (n0 + lc)];
  }
  __syncthreads();
  #pragma unroll
  for (int i = 0; i < 16; ++i) {
    const int lin = i * 256 + t;
    const int wr = lin >> 6, wc = lin & 63;   // wr: hid idx, wc: k idx
    const int k = k0 + wc;
    const int hid = n0 + wr;
    W1Tt[(size_t)(((k >> 5) * 4 + ((k >> 3) & 3)) * HID_DIM + hid) * 8 + (k & 7)] =
        f2bf(tile[wr][wc]);
  }
}

// ---- Kernel 2: zero d_out (it is poisoned to 0xAA before every call) ----
__global__ __launch_bounds__(256) void zero_out(float* __restrict__ out) {
  ((f32x4*)out)[blockIdx.x * 256 + threadIdx.x] = (f32x4){0.f, 0.f, 0.f, 0.f};
}

// ---- Kernel 3: 32-atom pooling; 128 threads (2 waves), 2 barriers ----
__global__ __launch_bounds__(128, 2) void pool_partial(
    const float* __restrict__ h, const u16* __restrict__ W1Tt,
    const float* __restrict__ b1, const float* __restrict__ W2,
    const float* __restrict__ b2, float* __restrict__ out) {
  // As: h bf16, 32 rows x 512; 16-B chunk c of row r at (c&~7)|((c^r)&7)
  __shared__ u16 As[ABLK * F_DIM];     // 32 KiB
  __shared__ float red[2][F_DIM];      // 4 KiB
  __shared__ float w_s[ABLK];

  const int blk = blockIdx.x;
  const int tid = threadIdx.x;
  const int wv = tid >> 6;       // wave 0..1 -> atoms wv*16..+15
  const int lane = tid & 63;
  const int quad = lane >> 4;
  const int cl = lane & 15;

  // --- Stage A: 64 KiB fp32 -> 32 KiB bf16 LDS, coalesced, 2 batches ---
  {
    const u32x4* hg = (const u32x4*)(h + (size_t)blk * ABLK * F_DIM);
    #pragma unroll
    for (int half = 0; half < 2; ++half) {
      u32x4 L[8], H[8];
      #pragma unroll
      for (int i = 0; i < 8; ++i) {
        const int u = (half * 8 + i) * 128 + tid;   // 32-B unit 0..2047
        L[i] = hg[2 * u];
        H[i] = hg[2 * u + 1];
      }
      #pragma unroll
      for (int i = 0; i < 8; ++i) {
        const int u = (half * 8 + i) * 128 + tid;
        const int row = u >> 6, c = u & 63;
        const int phys = (c & ~7) | ((c ^ row) & 7);
        *(bf16x8*)(As + row * F_DIM + phys * 8) = pack8(L[i], H[i]);
      }
    }
  }
  __syncthreads();   // barrier 1: As ready

  // --- Phase 1: T = h @ W1; wave wv does atoms wv*16..+15, all 128 hid ---
  // B straight from global W1Tt[ks][quad][hid][8] (L2-resident, no barrier)
  f32x4 acc[8];
  #pragma unroll
  for (int t = 0; t < 8; ++t) acc[t] = (f32x4){0.f, 0.f, 0.f, 0.f};

  const int ar = wv * 16 + cl;
  const u16* aBase = As + ar * F_DIM;
  const u16* gB = W1Tt + (quad * HID_DIM + cl) * 8;   // lane base

  for (int ks = 0; ks < 16; ++ks) {
    const int c = ks * 4 + quad;
    const int aphys = (c & ~7) | ((c ^ ar) & 7);
    bf16x8 afr = *(const bf16x8*)(aBase + aphys * 8);
    const u16* gk = gB + ks * 4096;                   // elems
    #pragma unroll
    for (int t = 0; t < 8; ++t) {
      bf16x8 bfr = *(const bf16x8*)(gk + t * 128);    // 4x256B segments/instr
      acc[t] = __builtin_amdgcn_mfma_f32_16x16x32_bf16(afr, bfr, acc[t], 0, 0, 0);
    }
  }

  // --- Epilogue: w[atom] = sigmoid(relu(T+b1)@W2 + b2) ---
  float psum[4] = {0.f, 0.f, 0.f, 0.f};
  #pragma unroll
  for (int t = 0; t < 8; ++t) {
    const int hid = t * 16 + cl;
    const float b1v = b1[hid];
    const float w2v = W2[hid];
    #pragma unroll
    for (int r = 0; r < 4; ++r) {
      float tv = fmaxf(acc[t][r] + b1v, 0.f);
      psum[r] = fmaf(tv, w2v, psum[r]);
    }
  }
  #pragma unroll
  for (int off = 1; off < 16; off <<= 1)
    #pragma unroll
    for (int r = 0; r < 4; ++r)
      psum[r] += __shfl_xor(psum[r], off, 64);
  if (cl == 0) {
    const float b2v = b2[0];
    #pragma unroll
    for (int r = 0; r < 4; ++r)
      w_s[wv * 16 + quad * 4 + r] = 1.f / (1.f + __expf(-(psum[r] + b2v)));
  }
  __syncthreads();   // wave reads only its own w_s half, but sync is cheap+safe

  // --- Phase 2: sum over own 16 atoms of w * h (LDS, 2-way-free reads) ---
  float facc[8] = {0.f, 0.f, 0.f, 0.f, 0.f, 0.f, 0.f, 0.f};
  #pragma unroll
  for (int i = 0; i < 16; ++i) {
    const int row = wv * 16 + i;
    const float wn = w_s[row];
    const int phys = (lane & ~7) | ((lane ^ row) & 7);
    bf16x8 hv = *(const bf16x8*)(As + row * F_DIM + phys * 8);
    u32x4 uv = __builtin_bit_cast(u32x4, hv);
    #pragma unroll
    for (int j = 0; j < 4; ++j) {
      facc[2 * j]     = fmaf(wn, __uint_as_float(uv[j] << 16), facc[2 * j]);
      facc[2 * j + 1] = fmaf(wn, __uint_as_float(uv[j] & 0xffff0000u), facc[2 * j + 1]);
    }
  }
  #pragma unroll
  for (int j = 0; j < 8; ++j) red[wv][lane * 8 + j] = facc[j];
  __syncthreads();   // barrier 2: red ready

  // --- Merge 2 waves, one atomic add per feature into out[m] ---
  {
    const int m = blk >> 2;        // 4 blocks per molecule
    const int f = tid * 4;         // 128 threads x 4 features
    #pragma unroll
    for (int j = 0; j < 4; ++j) {
      const float o = red[0][f + j] + red[1][f + j];
      unsafeAtomicAdd(out + (size_t)m * F_DIM + f + j, o);
    }
  }
}

extern "C" void kernel_launch(void* const* d_in, const int* in_sizes, int n_in,
                              void* d_out, int out_size, void* d_ws, size_t ws_size,
                              hipStream_t stream) {
  const float* h  = (const float*)d_in[0];   // [512,128,512] fp32
  const float* W1 = (const float*)d_in[1];   // [512,128] fp32
  const float* b1 = (const float*)d_in[2];   // [128] fp32
  const float* W2 = (const float*)d_in[3];   // [128,1] fp32
  const float* b2 = (const float*)d_in[4];   // [1] fp32
  float* out = (float*)d_out;                // [512,512] fp32

  u16* W1Tt = (u16*)d_ws;                    // 128 KiB

  transpose_w1<<<dim3(8, 2), 256, 0, stream>>>(W1, W1Tt);
  zero_out<<<256, 256, 0, stream>>>(out);
  pool_partial<<<NBLK, 128, 0, stream>>>(h, W1Tt, b1, W2, b2, out);
}